// Round 10
// baseline (390.037 us; speedup 1.0000x reference)
//
#include <hip/hip_runtime.h>
#include <stdint.h>

typedef __bf16 bf16x8 __attribute__((ext_vector_type(8)));
typedef float f32x4 __attribute__((ext_vector_type(4)));
typedef unsigned short u16x8 __attribute__((ext_vector_type(8)));

__device__ __forceinline__ unsigned short f2bf(float f){
  union { float f; unsigned u; } c; c.f = f;
  unsigned u = c.u;
  unsigned r = u + 0x7FFFu + ((u >> 16) & 1u);
  return (unsigned short)(r >> 16);
}

// ---------------- fused: fragment-major B pack (blocks 0..95) + dst histogram ----------------
// Bp[w][kb][c][lane][8]: lane l=(kg<<4)|r holds W[kb*32+kg*8 .. +8][w*64+c*16+r] as bf16.
__global__ void k_prehist(const int* __restrict__ ei, int E, int Nn, int* __restrict__ counts,
                          const float* __restrict__ W1, const float* __restrict__ W2,
                          const float* __restrict__ W3, unsigned short* __restrict__ p1,
                          unsigned short* __restrict__ p2, unsigned short* __restrict__ p3){
  int b = blockIdx.x;
  if (b < 96){
    int t = b*256 + threadIdx.x;   // [0, 3*8192)
    int which = t >> 13, li = t & 8191;
    const float* W = (which == 0) ? W1 : (which == 1) ? W2 : W3;
    unsigned short* P = (which == 0) ? p1 : (which == 1) ? p2 : p3;
    int l = li & 63, c = (li >> 6) & 3, kb = (li >> 8) & 7, w = li >> 11;
    int r = l & 15, kg = l >> 4;
    int col = w*64 + c*16 + r;
    int k0 = kb*32 + kg*8;
    unsigned short v[8];
    #pragma unroll
    for (int j = 0; j < 8; ++j) v[j] = f2bf(W[(size_t)(k0 + j)*256 + col]);
    *reinterpret_cast<uint4*>(P + (size_t)li*8) = *reinterpret_cast<const uint4*>(v);
  } else {
    int total = E + Nn;
    for (int e = (b - 96)*256 + threadIdx.x; e < total; e += (gridDim.x - 96)*256){
      int d = (e < E) ? ei[E + e] : (e - E);
      atomicAdd(&counts[d], 1);
    }
  }
}

__global__ __launch_bounds__(1024) void k_scan1(const int* __restrict__ counts, int* __restrict__ rowptr,
                                                int* __restrict__ bsum, int n){
  __shared__ int wsum[17];
  int tid = threadIdx.x, lane = tid & 63, wid = tid >> 6;
  int i = blockIdx.x*1024 + tid;
  int v = (i < n) ? counts[i] : 0;
  int iv = v;
  #pragma unroll
  for (int off = 1; off < 64; off <<= 1){
    int t = __shfl_up(iv, off, 64);
    if (lane >= off) iv += t;
  }
  if (lane == 63) wsum[wid] = iv;
  __syncthreads();
  if (tid == 0){
    int run = 0;
    for (int w = 0; w < 16; ++w){ int t = wsum[w]; wsum[w] = run; run += t; }
    wsum[16] = run;
  }
  __syncthreads();
  if (i < n) rowptr[i + 1] = iv + wsum[wid];
  if (tid == 0) bsum[blockIdx.x] = wsum[16];
}

__global__ __launch_bounds__(1024) void k_scan2(int* __restrict__ bsum, int nb){
  __shared__ int wsum[17];
  int tid = threadIdx.x, lane = tid & 63, wid = tid >> 6;
  int v = (tid < nb) ? bsum[tid] : 0;
  int iv = v;
  #pragma unroll
  for (int off = 1; off < 64; off <<= 1){
    int t = __shfl_up(iv, off, 64);
    if (lane >= off) iv += t;
  }
  if (lane == 63) wsum[wid] = iv;
  __syncthreads();
  if (tid == 0){
    int run = 0;
    for (int w = 0; w < 16; ++w){ int t = wsum[w]; wsum[w] = run; run += t; }
  }
  __syncthreads();
  if (tid < nb) bsum[tid] = iv + wsum[wid] - v;   // exclusive
}

// finalize rowptr and seed cursor[i] = rowptr[i] (segment start) in the same pass
__global__ void k_scan3(int* __restrict__ rowptr, const int* __restrict__ bsum,
                        const int* __restrict__ counts, int* __restrict__ cursor, int n){
  int i = blockIdx.x*blockDim.x + threadIdx.x;
  if (i == 0) rowptr[0] = 0;
  if (i < n){
    int v = rowptr[i + 1] + bsum[i >> 10];
    rowptr[i + 1] = v;
    cursor[i] = v - counts[i];
  }
}

__global__ void k_scatter(const int* __restrict__ ei, int E, int Nn,
                          int* __restrict__ cursor, int* __restrict__ srcs){
  int total = E + Nn;
  for (int e = blockIdx.x*blockDim.x + threadIdx.x; e < total; e += gridDim.x*blockDim.x){
    int s, d;
    if (e < E){ s = ei[e]; d = ei[E + e]; } else { s = d = e - E; }
    int pos = atomicAdd(&cursor[d], 1);
    srcs[pos] = s;
  }
}

// ---------------- pipelined GEMM: 2 tiles/block, fragment-major B, C^T epilogue ----------------
// While tile t computes, tile t+G's A-tile is loaded into registers (global wait off the
// critical path). B frags re-read per kb from L2-hot Bp (double-buffered in regs).
template<bool AF32>
__global__ __launch_bounds__(256) void k_gemm8(const void* __restrict__ Av,
                                               const unsigned short* __restrict__ Bp,
                                               const float* __restrict__ asrc,
                                               const float* __restrict__ adst,
                                               unsigned short* __restrict__ H,
                                               float* __restrict__ als,
                                               float* __restrict__ ald,
                                               int Nn, int T, int G){
  __shared__ unsigned short As[32][264];
  int tid = threadIdx.x;
  int w = tid >> 6, lane = tid & 63;       // w = head 0..3
  int r = lane & 15, kg = lane >> 4;

  const unsigned short* a16 = (const unsigned short*)Av;
  const float*          a32 = (const float*)Av;
  const unsigned short* bpw = Bp + ((size_t)w << 14);   // head base

  uint4  sreg[4];
  float4 sregf[4][2];

  auto load_tile = [&](int t){
    #pragma unroll
    for (int it = 0; it < 4; ++it){
      int li = it*256 + tid;
      int rr = li >> 5, c16 = li & 31;
      int gr = t*32 + rr; if (gr >= Nn) gr = Nn - 1;
      if (AF32){
        const float* ap = a32 + (size_t)gr*256 + c16*8;
        sregf[it][0] = *reinterpret_cast<const float4*>(ap);
        sregf[it][1] = *reinterpret_cast<const float4*>(ap + 4);
      } else {
        sreg[it] = *reinterpret_cast<const uint4*>(a16 + (size_t)gr*256 + c16*8);
      }
    }
  };
  auto write_lds = [&](){
    #pragma unroll
    for (int it = 0; it < 4; ++it){
      int li = it*256 + tid;
      int rr = li >> 5, c16 = li & 31;
      if (AF32){
        float4 v0 = sregf[it][0], v1 = sregf[it][1];
        union { uint4 q; unsigned short s[8]; } u;
        u.s[0]=f2bf(v0.x); u.s[1]=f2bf(v0.y); u.s[2]=f2bf(v0.z); u.s[3]=f2bf(v0.w);
        u.s[4]=f2bf(v1.x); u.s[5]=f2bf(v1.y); u.s[6]=f2bf(v1.z); u.s[7]=f2bf(v1.w);
        *reinterpret_cast<uint4*>(&As[rr][c16*8]) = u.q;
      } else {
        *reinterpret_cast<uint4*>(&As[rr][c16*8]) = sreg[it];
      }
    }
  };

  int t = blockIdx.x;
  if (t >= T) return;
  load_tile(t);

  for (;;){
    write_lds();
    __syncthreads();
    int tn = t + G;
    bool more = (tn < T);
    if (more) load_tile(tn);          // A prefetch in flight during compute + epilogue

    // kb=0 B frags (L2-hot)
    bf16x8 bf0[4], bf1[4];
    #pragma unroll
    for (int c = 0; c < 4; ++c)
      bf0[c] = *reinterpret_cast<const bf16x8*>(bpw + ((size_t)(c*64 + lane))*8);

    f32x4 acc[2][4] = {};
    #pragma unroll
    for (int kb = 0; kb < 8; ++kb){
      if (kb < 7){
        if (kb & 1){
          #pragma unroll
          for (int c = 0; c < 4; ++c)
            bf0[c] = *reinterpret_cast<const bf16x8*>(bpw + ((size_t)(((kb+1)*4 + c)*64 + lane))*8);
        } else {
          #pragma unroll
          for (int c = 0; c < 4; ++c)
            bf1[c] = *reinterpret_cast<const bf16x8*>(bpw + ((size_t)(((kb+1)*4 + c)*64 + lane))*8);
        }
      }
      bf16x8 a0 = *reinterpret_cast<const bf16x8*>(&As[r][kg*8 + kb*32]);
      bf16x8 a1 = *reinterpret_cast<const bf16x8*>(&As[16 + r][kg*8 + kb*32]);
      if (kb & 1){
        #pragma unroll
        for (int c = 0; c < 4; ++c){
          acc[0][c] = __builtin_amdgcn_mfma_f32_16x16x32_bf16(bf1[c], a0, acc[0][c], 0, 0, 0);
          acc[1][c] = __builtin_amdgcn_mfma_f32_16x16x32_bf16(bf1[c], a1, acc[1][c], 0, 0, 0);
        }
      } else {
        #pragma unroll
        for (int c = 0; c < 4; ++c){
          acc[0][c] = __builtin_amdgcn_mfma_f32_16x16x32_bf16(bf0[c], a0, acc[0][c], 0, 0, 0);
          acc[1][c] = __builtin_amdgcn_mfma_f32_16x16x32_bf16(bf0[c], a1, acc[1][c], 0, 0, 0);
        }
      }
    }

    int row0 = t*32;
    // C store: lane holds rows row0+n*16+r, features w*64+c*16+kg*4 .. +3 -> 8B packed stores
    #pragma unroll
    for (int n = 0; n < 2; ++n){
      int row = row0 + n*16 + r;
      if (row < Nn){
        #pragma unroll
        for (int c = 0; c < 4; ++c){
          ushort4 pk;
          pk.x = f2bf(acc[n][c][0]); pk.y = f2bf(acc[n][c][1]);
          pk.z = f2bf(acc[n][c][2]); pk.w = f2bf(acc[n][c][3]);
          *reinterpret_cast<ushort4*>(H + (size_t)row*256 + w*64 + c*16 + kg*4) = pk;
        }
      }
    }

    // fused attention logits: lane-local dot over 16 features, reduce across kg
    float4 as4[4], ad4[4];
    #pragma unroll
    for (int c = 0; c < 4; ++c){
      as4[c] = *reinterpret_cast<const float4*>(asrc + w*64 + c*16 + kg*4);
      ad4[c] = *reinterpret_cast<const float4*>(adst + w*64 + c*16 + kg*4);
    }
    #pragma unroll
    for (int n = 0; n < 2; ++n){
      float ps = 0.f, pd = 0.f;
      #pragma unroll
      for (int c = 0; c < 4; ++c){
        ps += acc[n][c][0]*as4[c].x + acc[n][c][1]*as4[c].y
            + acc[n][c][2]*as4[c].z + acc[n][c][3]*as4[c].w;
        pd += acc[n][c][0]*ad4[c].x + acc[n][c][1]*ad4[c].y
            + acc[n][c][2]*ad4[c].z + acc[n][c][3]*ad4[c].w;
      }
      ps += __shfl_xor(ps, 16, 64); ps += __shfl_xor(ps, 32, 64);
      pd += __shfl_xor(pd, 16, 64); pd += __shfl_xor(pd, 32, 64);
      int row = row0 + n*16 + r;
      if (kg == 0 && row < Nn){
        als[row*4 + w] = ps;
        ald[row*4 + w] = pd;
      }
    }

    if (!more) break;
    __syncthreads();                  // all As reads done; safe to overwrite
    t = tn;
  }
}

// ---------------- fused softmax + weighted gather (measured best: ~69us, UNCHANGED) ----------------
template<int MODE>
__global__ void k_gather3(const unsigned short* __restrict__ Hm, const int* __restrict__ rowptr,
                          const int* __restrict__ srcs, const float* __restrict__ als,
                          const float* __restrict__ ald, const float* __restrict__ bias,
                          unsigned short* __restrict__ actout, float* __restrict__ finalout, int Nn){
  int gid = blockIdx.x*blockDim.x + threadIdx.x;
  int node = gid >> 6, lane = gid & 63;
  if (node >= Nn) return;
  int half = lane >> 5;          // which edge of the pair
  int l32  = lane & 31;
  int fbase = l32 * 8;           // features fbase..fbase+7
  int hd = l32 >> 3;             // head of those features
  unsigned voff_feat = (unsigned)(l32 * 16);   // bytes into the 512B H row

  int beg = rowptr[node], deg = rowptr[node + 1] - beg;
  float4 adv = *reinterpret_cast<const float4*>(ald + (size_t)node*4);
  float aldh = (hd == 0) ? adv.x : (hd == 1) ? adv.y : (hd == 2) ? adv.z : adv.w;

  float acc[4][8];
  #pragma unroll
  for (int u = 0; u < 4; ++u)
    #pragma unroll
    for (int i = 0; i < 8; ++i) acc[u][i] = 0.f;
  float sw = 0.f;

  const char* Hb = (const char*)Hm;
  const char* Ab = (const char*)als;

  for (int cb = 0; cb < deg; cb += 64){
    int chunk = min(64, deg - cb);
    int mysrc = (cb + lane < deg) ? srcs[beg + cb + lane] : 0;
    int jmax8 = chunk & ~7;
    int j = 0;
    for (; j < jmax8; j += 8){
      #pragma unroll
      for (int u = 0; u < 4; ++u){
        int e0 = j + 2*u;
        int sA = __builtin_amdgcn_readlane(mysrc, e0);
        int sB = __builtin_amdgcn_readlane(mysrc, e0 + 1);
        int sM = half ? sB : sA;
        uint4 hw = *reinterpret_cast<const uint4*>(Hb + (unsigned)sM*512u + voff_feat);
        float av = *reinterpret_cast<const float*>(Ab + ((unsigned)sM << 4) + ((unsigned)hd << 2));
        float l = av + aldh; l = l > 0.f ? l : 0.2f*l;
        float wgt = __expf(l);
        sw += wgt;
        float h0 = __uint_as_float(hw.x << 16);
        float h1 = __uint_as_float(hw.x & 0xffff0000u);
        float h2 = __uint_as_float(hw.y << 16);
        float h3 = __uint_as_float(hw.y & 0xffff0000u);
        float h4 = __uint_as_float(hw.z << 16);
        float h5 = __uint_as_float(hw.z & 0xffff0000u);
        float h6 = __uint_as_float(hw.w << 16);
        float h7 = __uint_as_float(hw.w & 0xffff0000u);
        acc[u][0] = fmaf(wgt, h0, acc[u][0]);
        acc[u][1] = fmaf(wgt, h1, acc[u][1]);
        acc[u][2] = fmaf(wgt, h2, acc[u][2]);
        acc[u][3] = fmaf(wgt, h3, acc[u][3]);
        acc[u][4] = fmaf(wgt, h4, acc[u][4]);
        acc[u][5] = fmaf(wgt, h5, acc[u][5]);
        acc[u][6] = fmaf(wgt, h6, acc[u][6]);
        acc[u][7] = fmaf(wgt, h7, acc[u][7]);
      }
    }
    for (; j < chunk; j += 2){
      int eA = j;
      int eB = (j + 1 < chunk) ? (j + 1) : j;
      int sA = __builtin_amdgcn_readlane(mysrc, eA);
      int sB = __builtin_amdgcn_readlane(mysrc, eB);
      int sM = half ? sB : sA;
      uint4 hw = *reinterpret_cast<const uint4*>(Hb + (unsigned)sM*512u + voff_feat);
      float av = *reinterpret_cast<const float*>(Ab + ((unsigned)sM << 4) + ((unsigned)hd << 2));
      float l = av + aldh; l = l > 0.f ? l : 0.2f*l;
      float wgt = __expf(l);
      if (j + half >= chunk) wgt = 0.f;
      sw += wgt;
      float h0 = __uint_as_float(hw.x << 16);
      float h1 = __uint_as_float(hw.x & 0xffff0000u);
      float h2 = __uint_as_float(hw.y << 16);
      float h3 = __uint_as_float(hw.y & 0xffff0000u);
      float h4 = __uint_as_float(hw.z << 16);
      float h5 = __uint_as_float(hw.z & 0xffff0000u);
      float h6 = __uint_as_float(hw.w << 16);
      float h7 = __uint_as_float(hw.w & 0xffff0000u);
      acc[0][0] = fmaf(wgt, h0, acc[0][0]);
      acc[0][1] = fmaf(wgt, h1, acc[0][1]);
      acc[0][2] = fmaf(wgt, h2, acc[0][2]);
      acc[0][3] = fmaf(wgt, h3, acc[0][3]);
      acc[0][4] = fmaf(wgt, h4, acc[0][4]);
      acc[0][5] = fmaf(wgt, h5, acc[0][5]);
      acc[0][6] = fmaf(wgt, h6, acc[0][6]);
      acc[0][7] = fmaf(wgt, h7, acc[0][7]);
    }
  }

  float accf[8];
  #pragma unroll
  for (int i = 0; i < 8; ++i){
    float t = acc[0][i] + acc[1][i] + acc[2][i] + acc[3][i];
    t += __shfl_xor(t, 32, 64);
    accf[i] = t;
  }
  float s = sw + __shfl_xor(sw, 32, 64);
  float inv = 1.f / s;

  if (MODE == 0){
    if (lane < 32){
      float4 b0 = *reinterpret_cast<const float4*>(bias + fbase);
      float4 b1 = *reinterpret_cast<const float4*>(bias + fbase + 4);
      float o[8];
      o[0] = accf[0]*inv + b0.x; o[1] = accf[1]*inv + b0.y;
      o[2] = accf[2]*inv + b0.z; o[3] = accf[3]*inv + b0.w;
      o[4] = accf[4]*inv + b1.x; o[5] = accf[5]*inv + b1.y;
      o[6] = accf[6]*inv + b1.z; o[7] = accf[7]*inv + b1.w;
      u16x8 pk;
      #pragma unroll
      for (int i = 0; i < 8; ++i){
        float v = o[i];
        v = v > 0.f ? v : __expf(v) - 1.f;
        pk[i] = f2bf(v);
      }
      *reinterpret_cast<u16x8*>(actout + (size_t)node*256 + fbase) = pk;
    }
  } else {
    float v[8];
    #pragma unroll
    for (int i = 0; i < 8; ++i){
      float t = accf[i]*inv;
      t += __shfl_xor(t, 8, 64);
      t += __shfl_xor(t, 16, 64);
      v[i] = t;
    }
    int k = l32 & 7;
    float4 b0 = *reinterpret_cast<const float4*>(bias + k*8);
    float4 b1 = *reinterpret_cast<const float4*>(bias + k*8 + 4);
    v[0] = v[0]*0.25f + b0.x; v[1] = v[1]*0.25f + b0.y;
    v[2] = v[2]*0.25f + b0.z; v[3] = v[3]*0.25f + b0.w;
    v[4] = v[4]*0.25f + b1.x; v[5] = v[5]*0.25f + b1.y;
    v[6] = v[6]*0.25f + b1.z; v[7] = v[7]*0.25f + b1.w;
    float mx = v[0];
    #pragma unroll
    for (int i = 1; i < 8; ++i) mx = fmaxf(mx, v[i]);
    #pragma unroll
    for (int off = 1; off < 8; off <<= 1) mx = fmaxf(mx, __shfl_xor(mx, off, 64));
    float se = 0.f;
    #pragma unroll
    for (int i = 0; i < 8; ++i) se += __expf(v[i] - mx);
    #pragma unroll
    for (int off = 1; off < 8; off <<= 1) se += __shfl_xor(se, off, 64);
    float lse = mx + __logf(se);
    if (lane < 8){
      float4 o0, o1;
      o0.x = v[0]-lse; o0.y = v[1]-lse; o0.z = v[2]-lse; o0.w = v[3]-lse;
      o1.x = v[4]-lse; o1.y = v[5]-lse; o1.z = v[6]-lse; o1.w = v[7]-lse;
      float* dst = finalout + (size_t)node*64 + lane*8;
      *reinterpret_cast<float4*>(dst)     = o0;
      *reinterpret_cast<float4*>(dst + 4) = o1;
    }
  }
}

extern "C" void kernel_launch(void* const* d_in, const int* in_sizes, int n_in,
                              void* d_out, int out_size, void* d_ws, size_t ws_size,
                              hipStream_t stream){
  const float* x     = (const float*)d_in[0];
  const int*   ei    = (const int*)  d_in[1];
  const float* W1    = (const float*)d_in[2];
  const float* asrc1 = (const float*)d_in[3];
  const float* adst1 = (const float*)d_in[4];
  const float* b1    = (const float*)d_in[5];
  const float* W2    = (const float*)d_in[6];
  const float* asrc2 = (const float*)d_in[7];
  const float* adst2 = (const float*)d_in[8];
  const float* b2    = (const float*)d_in[9];
  const float* W3    = (const float*)d_in[10];
  const float* asrc3 = (const float*)d_in[11];
  const float* adst3 = (const float*)d_in[12];
  const float* b3    = (const float*)d_in[13];
  float* out = (float*)d_out;

  int N = in_sizes[0] / 256;
  int E = in_sizes[1] / 2;

  char* p = (char*)d_ws;
  auto carve = [&](size_t bytes){ void* r = (void*)p; p += (bytes + 511) & ~(size_t)511; return r; };
  unsigned short* bufA = (unsigned short*)carve((size_t)N*256*2);
  unsigned short* bufH = (unsigned short*)carve((size_t)N*256*2);
  unsigned short* bufB = (unsigned short*)carve((size_t)N*256*2);
  unsigned short* bp1  = (unsigned short*)carve(256*256*2);
  unsigned short* bp2  = (unsigned short*)carve(256*256*2);
  unsigned short* bp3  = (unsigned short*)carve(256*256*2);
  float* als    = (float*)carve((size_t)N*4*4);
  float* ald    = (float*)carve((size_t)N*4*4);
  int* rowptr   = (int*)carve((size_t)(N+1)*4);
  int* counts   = (int*)carve((size_t)N*4);
  int* cursor   = (int*)carve((size_t)N*4);
  int* bsum     = (int*)carve((size_t)1024*4);
  int* srcs     = (int*)carve((size_t)(E+N)*4);

  // CSR build + weight pack (pack fused into hist dispatch)
  hipMemsetAsync(counts, 0, (size_t)N*4, stream);
  k_prehist<<<96 + 2048, 256, 0, stream>>>(ei, E, N, counts, W1, W2, W3, bp1, bp2, bp3);
  int nb = (N + 1023) / 1024;
  k_scan1<<<nb, 1024, 0, stream>>>(counts, rowptr, bsum, N);
  k_scan2<<<1, 1024, 0, stream>>>(bsum, nb);
  k_scan3<<<(N + 255)/256, 256, 0, stream>>>(rowptr, bsum, counts, cursor, N);
  k_scatter<<<2048, 256, 0, stream>>>(ei, E, N, cursor, srcs);

  int T = (N + 31) / 32;             // 32-row tiles
  int G = (T + 1) / 2;               // two tiles per block, pipelined
  int nodeblocks = (N*64 + 255)/256;

  // layer 1 (A = x f32, converted during staging)
  k_gemm8<true><<<G, 256, 0, stream>>>(x, bp1, asrc1, adst1, bufH, als, ald, N, T, G);
  k_gather3<0><<<nodeblocks, 256, 0, stream>>>(bufH, rowptr, srcs, als, ald, b1, bufB, nullptr, N);
  // layer 2
  k_gemm8<false><<<G, 256, 0, stream>>>(bufB, bp2, asrc2, adst2, bufH, als, ald, N, T, G);
  k_gather3<0><<<nodeblocks, 256, 0, stream>>>(bufH, rowptr, srcs, als, ald, b2, bufA, nullptr, N);
  // layer 3
  k_gemm8<false><<<G, 256, 0, stream>>>(bufA, bp3, asrc3, adst3, bufH, als, ald, N, T, G);
  k_gather3<1><<<nodeblocks, 256, 0, stream>>>(bufH, rowptr, srcs, als, ald, b3, nullptr, out, N);
}

// Round 11
// 365.694 us; speedup vs baseline: 1.0666x; 1.0666x over previous
//
#include <hip/hip_runtime.h>
#include <stdint.h>

typedef __bf16 bf16x8 __attribute__((ext_vector_type(8)));
typedef float f32x4 __attribute__((ext_vector_type(4)));
typedef unsigned short u16x8 __attribute__((ext_vector_type(8)));

__device__ __forceinline__ unsigned short f2bf(float f){
  union { float f; unsigned u; } c; c.f = f;
  unsigned u = c.u;
  unsigned r = u + 0x7FFFu + ((u >> 16) & 1u);
  return (unsigned short)(r >> 16);
}

// ---------------- fused: fragment-major B pack (blocks 0..95) + dst histogram ----------------
// Bp[w][kb][c][lane][8]: lane l=(kg<<4)|r holds W[kb*32+kg*8 .. +8][w*64+c*16+r] as bf16.
__global__ void k_prehist(const int* __restrict__ ei, int E, int Nn, int* __restrict__ counts,
                          const float* __restrict__ W1, const float* __restrict__ W2,
                          const float* __restrict__ W3, unsigned short* __restrict__ p1,
                          unsigned short* __restrict__ p2, unsigned short* __restrict__ p3){
  int b = blockIdx.x;
  if (b < 96){
    int t = b*256 + threadIdx.x;   // [0, 3*8192)
    int which = t >> 13, li = t & 8191;
    const float* W = (which == 0) ? W1 : (which == 1) ? W2 : W3;
    unsigned short* P = (which == 0) ? p1 : (which == 1) ? p2 : p3;
    int l = li & 63, c = (li >> 6) & 3, kb = (li >> 8) & 7, w = li >> 11;
    int r = l & 15, kg = l >> 4;
    int col = w*64 + c*16 + r;
    int k0 = kb*32 + kg*8;
    unsigned short v[8];
    #pragma unroll
    for (int j = 0; j < 8; ++j) v[j] = f2bf(W[(size_t)(k0 + j)*256 + col]);
    *reinterpret_cast<uint4*>(P + (size_t)li*8) = *reinterpret_cast<const uint4*>(v);
  } else {
    int total = E + Nn;
    for (int e = (b - 96)*256 + threadIdx.x; e < total; e += (gridDim.x - 96)*256){
      int d = (e < E) ? ei[E + e] : (e - E);
      atomicAdd(&counts[d], 1);
    }
  }
}

__global__ __launch_bounds__(1024) void k_scan1(const int* __restrict__ counts, int* __restrict__ rowptr,
                                                int* __restrict__ bsum, int n){
  __shared__ int wsum[17];
  int tid = threadIdx.x, lane = tid & 63, wid = tid >> 6;
  int i = blockIdx.x*1024 + tid;
  int v = (i < n) ? counts[i] : 0;
  int iv = v;
  #pragma unroll
  for (int off = 1; off < 64; off <<= 1){
    int t = __shfl_up(iv, off, 64);
    if (lane >= off) iv += t;
  }
  if (lane == 63) wsum[wid] = iv;
  __syncthreads();
  if (tid == 0){
    int run = 0;
    for (int w = 0; w < 16; ++w){ int t = wsum[w]; wsum[w] = run; run += t; }
    wsum[16] = run;
  }
  __syncthreads();
  if (i < n) rowptr[i + 1] = iv + wsum[wid];
  if (tid == 0) bsum[blockIdx.x] = wsum[16];
}

__global__ __launch_bounds__(1024) void k_scan2(int* __restrict__ bsum, int nb){
  __shared__ int wsum[17];
  int tid = threadIdx.x, lane = tid & 63, wid = tid >> 6;
  int v = (tid < nb) ? bsum[tid] : 0;
  int iv = v;
  #pragma unroll
  for (int off = 1; off < 64; off <<= 1){
    int t = __shfl_up(iv, off, 64);
    if (lane >= off) iv += t;
  }
  if (lane == 63) wsum[wid] = iv;
  __syncthreads();
  if (tid == 0){
    int run = 0;
    for (int w = 0; w < 16; ++w){ int t = wsum[w]; wsum[w] = run; run += t; }
  }
  __syncthreads();
  if (tid < nb) bsum[tid] = iv + wsum[wid] - v;   // exclusive
}

// finalize rowptr and seed cursor[i] = rowptr[i] (segment start) in the same pass
__global__ void k_scan3(int* __restrict__ rowptr, const int* __restrict__ bsum,
                        const int* __restrict__ counts, int* __restrict__ cursor, int n){
  int i = blockIdx.x*blockDim.x + threadIdx.x;
  if (i == 0) rowptr[0] = 0;
  if (i < n){
    int v = rowptr[i + 1] + bsum[i >> 10];
    rowptr[i + 1] = v;
    cursor[i] = v - counts[i];
  }
}

__global__ void k_scatter(const int* __restrict__ ei, int E, int Nn,
                          int* __restrict__ cursor, int* __restrict__ srcs){
  int total = E + Nn;
  for (int e = blockIdx.x*blockDim.x + threadIdx.x; e < total; e += gridDim.x*blockDim.x){
    int s, d;
    if (e < E){ s = ei[e]; d = ei[E + e]; } else { s = d = e - E; }
    int pos = atomicAdd(&cursor[d], 1);
    srcs[pos] = s;
  }
}

// ---------------- GEMM (r8 verified best): 32-row tile, 4 waves, fragment-major B ----------------
// A staged into padded LDS (f32->bf16 fused for layer 1); B frags are contiguous 1KB
// coalesced loads from L2-resident Bp, double-buffered in registers; direct C stores;
// fused attention-logit epilogue.
template<bool AF32>
__global__ __launch_bounds__(256) void k_gemm6(const void* __restrict__ Av,
                                               const unsigned short* __restrict__ Bp,
                                               const float* __restrict__ asrc,
                                               const float* __restrict__ adst,
                                               unsigned short* __restrict__ H,
                                               float* __restrict__ als,
                                               float* __restrict__ ald,
                                               int Nn){
  __shared__ unsigned short As[32][264];
  int tid = threadIdx.x;
  int w = tid >> 6, lane = tid & 63;       // w = head 0..3
  int r = lane & 15, kg = lane >> 4;
  int row0 = blockIdx.x * 32;

  const unsigned short* a16 = (const unsigned short*)Av;
  const float*          a32 = (const float*)Av;
  const unsigned short* bpw = Bp + ((size_t)w << 14);   // head base: w*8*4*64*8

  // issue kb=0 B-frag loads first (independent of A staging)
  bf16x8 bf0[4], bf1[4];
  #pragma unroll
  for (int c = 0; c < 4; ++c)
    bf0[c] = *reinterpret_cast<const bf16x8*>(bpw + ((size_t)(c*64 + lane))*8);

  // stage A: 32 rows x 256 bf16 = 1024 x 16B chunks, 4 per thread, coalesced
  #pragma unroll
  for (int it = 0; it < 4; ++it){
    int li = it*256 + tid;
    int rr = li >> 5, c16 = li & 31;
    int gr = row0 + rr; if (gr >= Nn) gr = Nn - 1;
    if (AF32){
      const float* ap = a32 + (size_t)gr*256 + c16*8;
      float4 v0 = *reinterpret_cast<const float4*>(ap);
      float4 v1 = *reinterpret_cast<const float4*>(ap + 4);
      union { uint4 q; unsigned short s[8]; } u;
      u.s[0]=f2bf(v0.x); u.s[1]=f2bf(v0.y); u.s[2]=f2bf(v0.z); u.s[3]=f2bf(v0.w);
      u.s[4]=f2bf(v1.x); u.s[5]=f2bf(v1.y); u.s[6]=f2bf(v1.z); u.s[7]=f2bf(v1.w);
      *reinterpret_cast<uint4*>(&As[rr][c16*8]) = u.q;
    } else {
      uint4 v = *reinterpret_cast<const uint4*>(a16 + (size_t)gr*256 + c16*8);
      *reinterpret_cast<uint4*>(&As[rr][c16*8]) = v;
    }
  }
  __syncthreads();

  f32x4 acc[2][4] = {};
  #pragma unroll
  for (int kb = 0; kb < 8; ++kb){
    // prefetch next k-step's B frags while this step computes
    if (kb < 7){
      if (kb & 1){
        #pragma unroll
        for (int c = 0; c < 4; ++c)
          bf0[c] = *reinterpret_cast<const bf16x8*>(bpw + ((size_t)(((kb+1)*4 + c)*64 + lane))*8);
      } else {
        #pragma unroll
        for (int c = 0; c < 4; ++c)
          bf1[c] = *reinterpret_cast<const bf16x8*>(bpw + ((size_t)(((kb+1)*4 + c)*64 + lane))*8);
      }
    }
    bf16x8 a0 = *reinterpret_cast<const bf16x8*>(&As[r][kg*8 + kb*32]);
    bf16x8 a1 = *reinterpret_cast<const bf16x8*>(&As[16 + r][kg*8 + kb*32]);
    if (kb & 1){
      #pragma unroll
      for (int c = 0; c < 4; ++c){
        acc[0][c] = __builtin_amdgcn_mfma_f32_16x16x32_bf16(a0, bf1[c], acc[0][c], 0, 0, 0);
        acc[1][c] = __builtin_amdgcn_mfma_f32_16x16x32_bf16(a1, bf1[c], acc[1][c], 0, 0, 0);
      }
    } else {
      #pragma unroll
      for (int c = 0; c < 4; ++c){
        acc[0][c] = __builtin_amdgcn_mfma_f32_16x16x32_bf16(a0, bf0[c], acc[0][c], 0, 0, 0);
        acc[1][c] = __builtin_amdgcn_mfma_f32_16x16x32_bf16(a1, bf0[c], acc[1][c], 0, 0, 0);
      }
    }
  }

  // direct C store
  #pragma unroll
  for (int n = 0; n < 2; ++n){
    #pragma unroll
    for (int i = 0; i < 4; ++i){
      int row = row0 + n*16 + kg*4 + i;
      if (row < Nn){
        #pragma unroll
        for (int c = 0; c < 4; ++c)
          H[(size_t)row*256 + w*64 + c*16 + r] = f2bf(acc[n][c][i]);
      }
    }
  }

  // fused attention logits
  float as_c[4], ad_c[4];
  #pragma unroll
  for (int c = 0; c < 4; ++c){
    as_c[c] = asrc[w*64 + c*16 + r];
    ad_c[c] = adst[w*64 + c*16 + r];
  }
  #pragma unroll
  for (int n = 0; n < 2; ++n){
    #pragma unroll
    for (int i = 0; i < 4; ++i){
      float ps = acc[n][0][i]*as_c[0] + acc[n][1][i]*as_c[1]
               + acc[n][2][i]*as_c[2] + acc[n][3][i]*as_c[3];
      float pd = acc[n][0][i]*ad_c[0] + acc[n][1][i]*ad_c[1]
               + acc[n][2][i]*ad_c[2] + acc[n][3][i]*ad_c[3];
      #pragma unroll
      for (int off = 1; off < 16; off <<= 1){
        ps += __shfl_xor(ps, off, 64);
        pd += __shfl_xor(pd, off, 64);
      }
      int row = row0 + n*16 + kg*4 + i;
      if (r == 0 && row < Nn){
        als[row*4 + w] = ps;
        ald[row*4 + w] = pd;
      }
    }
  }
}

// ---------------- fused softmax + weighted gather (measured best: ~69us, UNCHANGED) ----------------
template<int MODE>
__global__ void k_gather3(const unsigned short* __restrict__ Hm, const int* __restrict__ rowptr,
                          const int* __restrict__ srcs, const float* __restrict__ als,
                          const float* __restrict__ ald, const float* __restrict__ bias,
                          unsigned short* __restrict__ actout, float* __restrict__ finalout, int Nn){
  int gid = blockIdx.x*blockDim.x + threadIdx.x;
  int node = gid >> 6, lane = gid & 63;
  if (node >= Nn) return;
  int half = lane >> 5;          // which edge of the pair
  int l32  = lane & 31;
  int fbase = l32 * 8;           // features fbase..fbase+7
  int hd = l32 >> 3;             // head of those features
  unsigned voff_feat = (unsigned)(l32 * 16);   // bytes into the 512B H row

  int beg = rowptr[node], deg = rowptr[node + 1] - beg;
  float4 adv = *reinterpret_cast<const float4*>(ald + (size_t)node*4);
  float aldh = (hd == 0) ? adv.x : (hd == 1) ? adv.y : (hd == 2) ? adv.z : adv.w;

  float acc[4][8];
  #pragma unroll
  for (int u = 0; u < 4; ++u)
    #pragma unroll
    for (int i = 0; i < 8; ++i) acc[u][i] = 0.f;
  float sw = 0.f;

  const char* Hb = (const char*)Hm;
  const char* Ab = (const char*)als;

  for (int cb = 0; cb < deg; cb += 64){
    int chunk = min(64, deg - cb);
    int mysrc = (cb + lane < deg) ? srcs[beg + cb + lane] : 0;
    int jmax8 = chunk & ~7;
    int j = 0;
    for (; j < jmax8; j += 8){
      #pragma unroll
      for (int u = 0; u < 4; ++u){
        int e0 = j + 2*u;
        int sA = __builtin_amdgcn_readlane(mysrc, e0);
        int sB = __builtin_amdgcn_readlane(mysrc, e0 + 1);
        int sM = half ? sB : sA;
        uint4 hw = *reinterpret_cast<const uint4*>(Hb + (unsigned)sM*512u + voff_feat);
        float av = *reinterpret_cast<const float*>(Ab + ((unsigned)sM << 4) + ((unsigned)hd << 2));
        float l = av + aldh; l = l > 0.f ? l : 0.2f*l;
        float wgt = __expf(l);
        sw += wgt;
        float h0 = __uint_as_float(hw.x << 16);
        float h1 = __uint_as_float(hw.x & 0xffff0000u);
        float h2 = __uint_as_float(hw.y << 16);
        float h3 = __uint_as_float(hw.y & 0xffff0000u);
        float h4 = __uint_as_float(hw.z << 16);
        float h5 = __uint_as_float(hw.z & 0xffff0000u);
        float h6 = __uint_as_float(hw.w << 16);
        float h7 = __uint_as_float(hw.w & 0xffff0000u);
        acc[u][0] = fmaf(wgt, h0, acc[u][0]);
        acc[u][1] = fmaf(wgt, h1, acc[u][1]);
        acc[u][2] = fmaf(wgt, h2, acc[u][2]);
        acc[u][3] = fmaf(wgt, h3, acc[u][3]);
        acc[u][4] = fmaf(wgt, h4, acc[u][4]);
        acc[u][5] = fmaf(wgt, h5, acc[u][5]);
        acc[u][6] = fmaf(wgt, h6, acc[u][6]);
        acc[u][7] = fmaf(wgt, h7, acc[u][7]);
      }
    }
    for (; j < chunk; j += 2){
      int eA = j;
      int eB = (j + 1 < chunk) ? (j + 1) : j;
      int sA = __builtin_amdgcn_readlane(mysrc, eA);
      int sB = __builtin_amdgcn_readlane(mysrc, eB);
      int sM = half ? sB : sA;
      uint4 hw = *reinterpret_cast<const uint4*>(Hb + (unsigned)sM*512u + voff_feat);
      float av = *reinterpret_cast<const float*>(Ab + ((unsigned)sM << 4) + ((unsigned)hd << 2));
      float l = av + aldh; l = l > 0.f ? l : 0.2f*l;
      float wgt = __expf(l);
      if (j + half >= chunk) wgt = 0.f;
      sw += wgt;
      float h0 = __uint_as_float(hw.x << 16);
      float h1 = __uint_as_float(hw.x & 0xffff0000u);
      float h2 = __uint_as_float(hw.y << 16);
      float h3 = __uint_as_float(hw.y & 0xffff0000u);
      float h4 = __uint_as_float(hw.z << 16);
      float h5 = __uint_as_float(hw.z & 0xffff0000u);
      float h6 = __uint_as_float(hw.w << 16);
      float h7 = __uint_as_float(hw.w & 0xffff0000u);
      acc[0][0] = fmaf(wgt, h0, acc[0][0]);
      acc[0][1] = fmaf(wgt, h1, acc[0][1]);
      acc[0][2] = fmaf(wgt, h2, acc[0][2]);
      acc[0][3] = fmaf(wgt, h3, acc[0][3]);
      acc[0][4] = fmaf(wgt, h4, acc[0][4]);
      acc[0][5] = fmaf(wgt, h5, acc[0][5]);
      acc[0][6] = fmaf(wgt, h6, acc[0][6]);
      acc[0][7] = fmaf(wgt, h7, acc[0][7]);
    }
  }

  float accf[8];
  #pragma unroll
  for (int i = 0; i < 8; ++i){
    float t = acc[0][i] + acc[1][i] + acc[2][i] + acc[3][i];
    t += __shfl_xor(t, 32, 64);
    accf[i] = t;
  }
  float s = sw + __shfl_xor(sw, 32, 64);
  float inv = 1.f / s;

  if (MODE == 0){
    if (lane < 32){
      float4 b0 = *reinterpret_cast<const float4*>(bias + fbase);
      float4 b1 = *reinterpret_cast<const float4*>(bias + fbase + 4);
      float o[8];
      o[0] = accf[0]*inv + b0.x; o[1] = accf[1]*inv + b0.y;
      o[2] = accf[2]*inv + b0.z; o[3] = accf[3]*inv + b0.w;
      o[4] = accf[4]*inv + b1.x; o[5] = accf[5]*inv + b1.y;
      o[6] = accf[6]*inv + b1.z; o[7] = accf[7]*inv + b1.w;
      u16x8 pk;
      #pragma unroll
      for (int i = 0; i < 8; ++i){
        float v = o[i];
        v = v > 0.f ? v : __expf(v) - 1.f;
        pk[i] = f2bf(v);
      }
      *reinterpret_cast<u16x8*>(actout + (size_t)node*256 + fbase) = pk;
    }
  } else {
    float v[8];
    #pragma unroll
    for (int i = 0; i < 8; ++i){
      float t = accf[i]*inv;
      t += __shfl_xor(t, 8, 64);
      t += __shfl_xor(t, 16, 64);
      v[i] = t;
    }
    int k = l32 & 7;
    float4 b0 = *reinterpret_cast<const float4*>(bias + k*8);
    float4 b1 = *reinterpret_cast<const float4*>(bias + k*8 + 4);
    v[0] = v[0]*0.25f + b0.x; v[1] = v[1]*0.25f + b0.y;
    v[2] = v[2]*0.25f + b0.z; v[3] = v[3]*0.25f + b0.w;
    v[4] = v[4]*0.25f + b1.x; v[5] = v[5]*0.25f + b1.y;
    v[6] = v[6]*0.25f + b1.z; v[7] = v[7]*0.25f + b1.w;
    float mx = v[0];
    #pragma unroll
    for (int i = 1; i < 8; ++i) mx = fmaxf(mx, v[i]);
    #pragma unroll
    for (int off = 1; off < 8; off <<= 1) mx = fmaxf(mx, __shfl_xor(mx, off, 64));
    float se = 0.f;
    #pragma unroll
    for (int i = 0; i < 8; ++i) se += __expf(v[i] - mx);
    #pragma unroll
    for (int off = 1; off < 8; off <<= 1) se += __shfl_xor(se, off, 64);
    float lse = mx + __logf(se);
    if (lane < 8){
      float4 o0, o1;
      o0.x = v[0]-lse; o0.y = v[1]-lse; o0.z = v[2]-lse; o0.w = v[3]-lse;
      o1.x = v[4]-lse; o1.y = v[5]-lse; o1.z = v[6]-lse; o1.w = v[7]-lse;
      float* dst = finalout + (size_t)node*64 + lane*8;
      *reinterpret_cast<float4*>(dst)     = o0;
      *reinterpret_cast<float4*>(dst + 4) = o1;
    }
  }
}

extern "C" void kernel_launch(void* const* d_in, const int* in_sizes, int n_in,
                              void* d_out, int out_size, void* d_ws, size_t ws_size,
                              hipStream_t stream){
  const float* x     = (const float*)d_in[0];
  const int*   ei    = (const int*)  d_in[1];
  const float* W1    = (const float*)d_in[2];
  const float* asrc1 = (const float*)d_in[3];
  const float* adst1 = (const float*)d_in[4];
  const float* b1    = (const float*)d_in[5];
  const float* W2    = (const float*)d_in[6];
  const float* asrc2 = (const float*)d_in[7];
  const float* adst2 = (const float*)d_in[8];
  const float* b2    = (const float*)d_in[9];
  const float* W3    = (const float*)d_in[10];
  const float* asrc3 = (const float*)d_in[11];
  const float* adst3 = (const float*)d_in[12];
  const float* b3    = (const float*)d_in[13];
  float* out = (float*)d_out;

  int N = in_sizes[0] / 256;
  int E = in_sizes[1] / 2;

  char* p = (char*)d_ws;
  auto carve = [&](size_t bytes){ void* r = (void*)p; p += (bytes + 511) & ~(size_t)511; return r; };
  unsigned short* bufA = (unsigned short*)carve((size_t)N*256*2);
  unsigned short* bufH = (unsigned short*)carve((size_t)N*256*2);
  unsigned short* bufB = (unsigned short*)carve((size_t)N*256*2);
  unsigned short* bp1  = (unsigned short*)carve(256*256*2);
  unsigned short* bp2  = (unsigned short*)carve(256*256*2);
  unsigned short* bp3  = (unsigned short*)carve(256*256*2);
  float* als    = (float*)carve((size_t)N*4*4);
  float* ald    = (float*)carve((size_t)N*4*4);
  int* rowptr   = (int*)carve((size_t)(N+1)*4);
  int* counts   = (int*)carve((size_t)N*4);
  int* cursor   = (int*)carve((size_t)N*4);
  int* bsum     = (int*)carve((size_t)1024*4);
  int* srcs     = (int*)carve((size_t)(E+N)*4);

  // CSR build + weight pack (pack fused into hist dispatch)
  hipMemsetAsync(counts, 0, (size_t)N*4, stream);
  k_prehist<<<96 + 2048, 256, 0, stream>>>(ei, E, N, counts, W1, W2, W3, bp1, bp2, bp3);
  int nb = (N + 1023) / 1024;
  k_scan1<<<nb, 1024, 0, stream>>>(counts, rowptr, bsum, N);
  k_scan2<<<1, 1024, 0, stream>>>(bsum, nb);
  k_scan3<<<(N + 255)/256, 256, 0, stream>>>(rowptr, bsum, counts, cursor, N);
  k_scatter<<<2048, 256, 0, stream>>>(ei, E, N, cursor, srcs);

  int gemm_grid  = (N + 31) / 32;
  int nodeblocks = (N*64 + 255)/256;

  // layer 1 (A = x f32, converted during staging)
  k_gemm6<true><<<gemm_grid, 256, 0, stream>>>(x, bp1, asrc1, adst1, bufH, als, ald, N);
  k_gather3<0><<<nodeblocks, 256, 0, stream>>>(bufH, rowptr, srcs, als, ald, b1, bufB, nullptr, N);
  // layer 2
  k_gemm6<false><<<gemm_grid, 256, 0, stream>>>(bufB, bp2, asrc2, adst2, bufH, als, ald, N);
  k_gather3<0><<<nodeblocks, 256, 0, stream>>>(bufH, rowptr, srcs, als, ald, b2, bufA, nullptr, N);
  // layer 3
  k_gemm6<false><<<gemm_grid, 256, 0, stream>>>(bufA, bp3, asrc3, adst3, bufH, als, ald, N);
  k_gather3<1><<<nodeblocks, 256, 0, stream>>>(bufH, rowptr, srcs, als, ald, b3, nullptr, out, N);
}